// Round 1
// baseline (33.686 us; speedup 1.0000x reference)
//
#include <hip/hip_runtime.h>
#include <hip/hip_bf16.h>
#include <math.h>

#define NAT 192
#define PIF 3.14159274101257324f

__device__ __forceinline__ float app_gauss(float x) {
    // reference: a = 1/(1+x/64+1e-8); return (a^2^5)^2 = a^64
    float a = 1.0f / (1.0f + x * (1.0f / 64.0f) + 1e-8f);
    a = a * a;  // a^2
    a = a * a;  // a^4
    a = a * a;  // a^8
    a = a * a;  // a^16
    a = a * a;  // a^32
    return a * a;  // a^64
}

__global__ __launch_bounds__(256) void desc_kernel(
    const float* __restrict__ pos, const float* __restrict__ spec,
    float* __restrict__ desc)
{
    const int i = blockIdx.x;
    const int t = threadIdx.x;

    __shared__ float px[NAT], py[NAT], pz[NAT], sp[NAT];
    __shared__ float rn_s[NAT], w6[NAT];
    __shared__ float cux[NAT], cuy[NAT], cuz[NAT], crr[NAT], cpw[NAT];
    __shared__ int wave_cnt[4];
    __shared__ float redbuf[256];
    __shared__ float Gs[64];

    for (int j = t; j < NAT; j += 256) {
        px[j] = pos[3 * j + 0];
        py[j] = pos[3 * j + 1];
        pz[j] = pos[3 * j + 2];
        sp[j] = spec[j];
    }
    if (t < 64) Gs[t] = 0.0f;
    __syncthreads();

    const float xi = px[i], yi = py[i], zi = pz[i];

    // ---- per-j: rnorm, radial weight, angular-cutoff candidates ----
    float dx = 0.f, dy = 0.f, dz = 0.f, rn = 0.f, pw = 0.f;
    bool pred = false;
    if (t < NAT) {
        dx = xi - px[t];
        dy = yi - py[t];
        dz = zi - pz[t];
        rn = sqrtf(dx * dx + dy * dy + dz * dz + 1e-12f);
        rn_s[t] = rn;
        float f6 = (rn <= 6.0f) ? 0.5f * (1.0f + cosf(PIF * rn / 6.0f)) : 0.0f;
        w6[t] = sp[t] * f6;
        if (rn <= 4.0f) {   // beyond rc_ang the pair weight is exactly 0
            pred = true;
            float f4 = 0.5f * (1.0f + cosf(PIF * rn / 4.0f));
            pw = sp[t] * f4;
        }
    }
    // deterministic compaction: per-wave ballot + prefix
    unsigned long long m = __ballot(pred);
    const int lane = t & 63, wv = t >> 6;
    if (lane == 0) wave_cnt[wv] = __popcll(m);
    __syncthreads();
    int base = 0;
    for (int w = 0; w < wv; ++w) base += wave_cnt[w];
    if (pred) {
        int slot = base + __popcll(m & ((1ull << lane) - 1ull));
        float inv = 1.0f / (rn + 1e-20f);
        cux[slot] = dx * inv;
        cuy[slot] = dy * inv;
        cuz[slot] = dz * inv;
        crr[slot] = rn;
        cpw[slot] = pw;
    }
    const int n = wave_cnt[0] + wave_cnt[1] + wave_cnt[2] + wave_cnt[3];
    __syncthreads();

    // ---- radial: thread = (s in 0..31, group g in 0..7), 24 j's each ----
    {
        const int s = t & 31, g = t >> 5;
        const float Rs = 0.25f + (float)s * 0.1796875f;  // (6-0.25)/32
        float acc = 0.0f;
        for (int j = g; j < NAT; j += 8) {
            float d = rn_s[j] - Rs;
            acc += w6[j] * app_gauss(0.5f * d * d);
        }
        redbuf[s * 8 + g] = acc;
    }

    // ---- angular: full n x n pair loop over the compacted list ----
    // float32 cos/sin of theta_s = t*pi/8 (t=4 matches np.cos(f32(pi/2)))
    const float CT[8] = {1.0f, 0.92387953f, 0.70710678f, 0.38268343f,
                         -4.37113883e-08f, -0.38268343f, -0.70710678f, -0.92387953f};
    const float ST[8] = {0.0f, 0.38268343f, 0.70710678f, 0.92387953f,
                         1.0f, 0.92387953f, 0.70710678f, 0.38268343f};

    float acc[8][8];
#pragma unroll
    for (int ss = 0; ss < 8; ++ss)
#pragma unroll
        for (int tt = 0; tt < 8; ++tt) acc[ss][tt] = 0.0f;

    const int npairs = n * n;
    for (int p = t; p < npairs; p += 256) {
        int a = p / n, b = p - a * n;
        float c = cux[a] * cux[b] + cuy[a] * cuy[b] + cuz[a] * cuz[b];
        float s2 = 1.0f - c * c;
        s2 = s2 < 0.0f ? 0.0f : s2;
        float sT = sqrtf(s2 + 1e-6f);
        float P = cpw[a] * cpw[b];
        float rr = 0.5f * (crr[a] + crr[b]);
        float angv[8];
#pragma unroll
        for (int tt = 0; tt < 8; ++tt) {
            float bse = 0.5f * (1.0f + c * CT[tt] + sT * ST[tt]);
            float b2v = bse * bse;
            float b4v = b2v * b2v;
            angv[tt] = b4v * b4v;  // ^8 = zeta
        }
#pragma unroll
        for (int ss = 0; ss < 8; ++ss) {
            float d = rr - (0.25f + (float)ss * 0.46875f);  // (4-0.25)/8
            float rg = app_gauss(0.5f * d * d) * P;
#pragma unroll
            for (int tt = 0; tt < 8; ++tt)
                acc[ss][tt] += rg * angv[tt];
        }
    }

    // reduce 64 accumulators across 256 threads: wave shuffle + LDS atomic
#pragma unroll
    for (int v = 0; v < 64; ++v) {
        float val = acc[v >> 3][v & 7];
#pragma unroll
        for (int o = 32; o > 0; o >>= 1) val += __shfl_xor(val, o, 64);
        if (lane == 0) atomicAdd(&Gs[v], val);
    }
    __syncthreads();

    if (t < 32) {
        float r = 0.0f;
#pragma unroll
        for (int g = 0; g < 8; ++g) r += redbuf[t * 8 + g];
        desc[i * 96 + t] = r;
    }
    if (t < 64) desc[i * 96 + 32 + t] = Gs[t];  // layout: s*8 + t
}

__global__ __launch_bounds__(128) void mlp_kernel(
    const float* __restrict__ desc,
    const float* __restrict__ W1, const float* __restrict__ b1,
    const float* __restrict__ W2, const float* __restrict__ b2,
    const float* __restrict__ W3, const float* __restrict__ b3,
    float* __restrict__ e_at)
{
    const int i = blockIdx.x;
    const int nidx = threadIdx.x;
    __shared__ float d_s[96], h_s[128], wsum[2];

    if (nidx < 96) d_s[nidx] = desc[i * 96 + nidx];
    __syncthreads();

    float acc = b1[nidx];
    for (int f = 0; f < 96; ++f) acc += d_s[f] * W1[f * 128 + nidx];
    h_s[nidx] = tanhf(acc);
    __syncthreads();

    acc = b2[nidx];
    for (int f = 0; f < 128; ++f) acc += h_s[f] * W2[f * 128 + nidx];
    float h2 = tanhf(acc);

    float partial = h2 * W3[nidx];
#pragma unroll
    for (int o = 32; o > 0; o >>= 1) partial += __shfl_xor(partial, o, 64);
    if ((nidx & 63) == 0) wsum[nidx >> 6] = partial;
    __syncthreads();
    if (nidx == 0) e_at[i] = wsum[0] + wsum[1] + b3[0];
}

__global__ __launch_bounds__(256) void sum_kernel(
    const float* __restrict__ e_at, float* __restrict__ out)
{
    const int t = threadIdx.x;
    float v = (t < NAT) ? e_at[t] : 0.0f;
#pragma unroll
    for (int o = 32; o > 0; o >>= 1) v += __shfl_xor(v, o, 64);
    __shared__ float ws_[4];
    if ((t & 63) == 0) ws_[t >> 6] = v;
    __syncthreads();
    if (t == 0) out[0] = ws_[0] + ws_[1] + ws_[2] + ws_[3];
}

extern "C" void kernel_launch(void* const* d_in, const int* in_sizes, int n_in,
                              void* d_out, int out_size, void* d_ws, size_t ws_size,
                              hipStream_t stream) {
    const float* pos  = (const float*)d_in[0];
    const float* spec = (const float*)d_in[1];
    const float* W1   = (const float*)d_in[2];
    const float* b1   = (const float*)d_in[3];
    const float* W2   = (const float*)d_in[4];
    const float* b2   = (const float*)d_in[5];
    const float* W3   = (const float*)d_in[6];
    const float* b3   = (const float*)d_in[7];

    float* desc = (float*)d_ws;                 // 192*96 floats
    float* e_at = desc + NAT * 96;              // 192 floats

    desc_kernel<<<NAT, 256, 0, stream>>>(pos, spec, desc);
    mlp_kernel<<<NAT, 128, 0, stream>>>(desc, W1, b1, W2, b2, W3, b3, e_at);
    sum_kernel<<<1, 256, 0, stream>>>(e_at, (float*)d_out);
}

// Round 2
// 24.118 us; speedup vs baseline: 1.3967x; 1.3967x over previous
//
#include <hip/hip_runtime.h>
#include <hip/hip_bf16.h>
#include <math.h>

#define NAT 192
#define PIF 3.14159274101257324f

__device__ __forceinline__ float app_gauss(float x) {
    // reference: a = 1/(1+x/64+1e-8); a^64 via 6 squarings
    float a = 1.0f / (1.0f + x * (1.0f / 64.0f) + 1e-8f);
    a = a * a; a = a * a; a = a * a; a = a * a; a = a * a;
    return a * a;
}

__global__ __launch_bounds__(256) void fused_kernel(
    const float* __restrict__ pos, const float* __restrict__ spec,
    const float* __restrict__ W1, const float* __restrict__ b1,
    const float* __restrict__ W2, const float* __restrict__ b2,
    const float* __restrict__ W3, const float* __restrict__ b3,
    float* __restrict__ e_at, unsigned int* __restrict__ counter,
    float* __restrict__ out)
{
    const int i = blockIdx.x;
    const int t = threadIdx.x;
    const int lane = t & 63, wv = t >> 6;

    __shared__ float px[NAT], py[NAT], pz[NAT], sp[NAT];
    __shared__ float rn_s[NAT], w6[NAT];
    __shared__ float cux[NAT], cuy[NAT], cuz[NAT], crr[NAT], cpw[NAT];
    __shared__ int wave_cnt[4];
    __shared__ float redbuf[256];     // radial partials
    __shared__ float wavebuf[256];    // butterfly per-wave results
    __shared__ float desc_s[96];
    __shared__ float part[2][128];
    __shared__ float hbuf[128];
    __shared__ float h2buf[128];
    __shared__ unsigned int ticket_s;
    __shared__ float final4[4];

    for (int j = t; j < NAT; j += 256) {
        px[j] = pos[3 * j + 0];
        py[j] = pos[3 * j + 1];
        pz[j] = pos[3 * j + 2];
        sp[j] = spec[j];
    }
    __syncthreads();

    const float xi = px[i], yi = py[i], zi = pz[i];

    // ---- per-j: rnorm, radial weight, angular-cutoff candidates ----
    float dx = 0.f, dy = 0.f, dz = 0.f, rn = 0.f, pw = 0.f;
    bool pred = false;
    if (t < NAT) {
        dx = xi - px[t];
        dy = yi - py[t];
        dz = zi - pz[t];
        rn = sqrtf(dx * dx + dy * dy + dz * dz + 1e-12f);
        rn_s[t] = rn;
        float f6 = (rn <= 6.0f) ? 0.5f * (1.0f + cosf(PIF * rn / 6.0f)) : 0.0f;
        w6[t] = sp[t] * f6;
        if (rn <= 4.0f) {   // beyond rc_ang pair weight is exactly 0
            pred = true;
            float f4 = 0.5f * (1.0f + cosf(PIF * rn / 4.0f));
            pw = sp[t] * f4;
        }
    }
    // deterministic compaction: per-wave ballot + prefix
    unsigned long long m = __ballot(pred);
    if (lane == 0) wave_cnt[wv] = __popcll(m);
    __syncthreads();
    int base = 0;
    for (int w = 0; w < wv; ++w) base += wave_cnt[w];
    if (pred) {
        int slot = base + __popcll(m & ((1ull << lane) - 1ull));
        float inv = 1.0f / (rn + 1e-20f);
        cux[slot] = dx * inv;
        cuy[slot] = dy * inv;
        cuz[slot] = dz * inv;
        crr[slot] = rn;
        cpw[slot] = pw;
    }
    const int nn = wave_cnt[0] + wave_cnt[1] + wave_cnt[2] + wave_cnt[3];
    __syncthreads();

    // ---- radial: thread = (s 0..31, g 0..7), strided over j ----
    {
        const int s = t & 31, g = t >> 5;
        const float Rs = 0.25f + (float)s * 0.1796875f;  // (6-0.25)/32
        float acc = 0.0f;
        for (int j = g; j < NAT; j += 8) {
            float d = rn_s[j] - Rs;
            acc += w6[j] * app_gauss(0.5f * d * d);
        }
        redbuf[s * 8 + g] = acc;
    }

    // ---- angular: pair loop over compacted list ----
    const float CT[8] = {1.0f, 0.92387953f, 0.70710678f, 0.38268343f,
                         -4.37113883e-08f, -0.38268343f, -0.70710678f, -0.92387953f};
    const float ST[8] = {0.0f, 0.38268343f, 0.70710678f, 0.92387953f,
                         1.0f, 0.92387953f, 0.70710678f, 0.38268343f};

    float av[64];
#pragma unroll
    for (int v = 0; v < 64; ++v) av[v] = 0.0f;

    const int npairs = nn * nn;
    for (int p = t; p < npairs; p += 256) {
        int a = p / nn, b = p - a * nn;
        float c = cux[a] * cux[b] + cuy[a] * cuy[b] + cuz[a] * cuz[b];
        float s2 = 1.0f - c * c;
        s2 = s2 < 0.0f ? 0.0f : s2;
        float sT = sqrtf(s2 + 1e-6f);
        float P = cpw[a] * cpw[b];
        float rr = 0.5f * (crr[a] + crr[b]);
        float angv[8];
#pragma unroll
        for (int tt = 0; tt < 8; ++tt) {
            float bse = 0.5f * (1.0f + c * CT[tt] + sT * ST[tt]);
            float b2v = bse * bse;
            float b4v = b2v * b2v;
            angv[tt] = b4v * b4v;  // ^zeta=8
        }
#pragma unroll
        for (int ss = 0; ss < 8; ++ss) {
            float d = rr - (0.25f + (float)ss * 0.46875f);  // (4-0.25)/8
            float rg = app_gauss(0.5f * d * d) * P;
#pragma unroll
            for (int tt = 0; tt < 8; ++tt)
                av[ss * 8 + tt] += rg * angv[tt];
        }
    }

    // ---- multi-value butterfly: lane l ends with total of value l ----
#define STAGE(h)                                                         \
    {                                                                    \
        const bool up = (lane & h) != 0;                                 \
        _Pragma("unroll")                                                \
        for (int k = 0; k < h; ++k) {                                    \
            float mine   = up ? av[k + h] : av[k];                       \
            float theirs = up ? av[k] : av[k + h];                       \
            av[k] = mine + __shfl_xor(theirs, h, 64);                    \
        }                                                                \
    }
    STAGE(32) STAGE(16) STAGE(8) STAGE(4) STAGE(2) STAGE(1)
#undef STAGE
    wavebuf[wv * 64 + lane] = av[0];
    __syncthreads();

    if (t < 32) {
        float r = 0.0f;
#pragma unroll
        for (int g = 0; g < 8; ++g) r += redbuf[t * 8 + g];
        desc_s[t] = r;
    }
    if (t < 64)
        desc_s[32 + t] = wavebuf[t] + wavebuf[64 + t] + wavebuf[128 + t] + wavebuf[192 + t];
    __syncthreads();

    // ---- MLP: 2 threads per neuron ----
    const int nidx = t & 127, hh = t >> 7;
    {
        float a1 = (hh == 0) ? b1[nidx] : 0.0f;
        const int f0 = hh * 48;
        for (int f = f0; f < f0 + 48; ++f) a1 += desc_s[f] * W1[f * 128 + nidx];
        part[hh][nidx] = a1;
    }
    __syncthreads();
    if (t < 128) hbuf[t] = tanhf(part[0][t] + part[1][t]);
    __syncthreads();
    {
        float a2 = (hh == 0) ? b2[nidx] : 0.0f;
        const int f0 = hh * 64;
        for (int f = f0; f < f0 + 64; ++f) a2 += hbuf[f] * W2[f * 128 + nidx];
        part[hh][nidx] = a2;
    }
    __syncthreads();
    if (t < 128) h2buf[t] = tanhf(part[0][t] + part[1][t]) * W3[t];
    __syncthreads();

    if (t < 64) {
        float v = h2buf[t] + h2buf[t + 64];
#pragma unroll
        for (int o = 32; o > 0; o >>= 1) v += __shfl_xor(v, o, 64);
        if (t == 0) {
            float e_val = v + b3[0];
            __hip_atomic_store(&e_at[i], e_val, __ATOMIC_RELEASE, __HIP_MEMORY_SCOPE_AGENT);
            unsigned int tk = __hip_atomic_fetch_add(counter, 1u, __ATOMIC_ACQ_REL,
                                                     __HIP_MEMORY_SCOPE_AGENT);
            ticket_s = tk;
        }
    }
    __syncthreads();

    // ---- last block: deterministic final sum (fixed order over e_at) ----
    if (ticket_s == NAT - 1) {
        float v = (t < NAT)
                      ? __hip_atomic_load(&e_at[t], __ATOMIC_ACQUIRE, __HIP_MEMORY_SCOPE_AGENT)
                      : 0.0f;
#pragma unroll
        for (int o = 32; o > 0; o >>= 1) v += __shfl_xor(v, o, 64);
        if (lane == 0) final4[wv] = v;
        __syncthreads();
        if (t == 0) out[0] = final4[0] + final4[1] + final4[2] + final4[3];
    }
}

extern "C" void kernel_launch(void* const* d_in, const int* in_sizes, int n_in,
                              void* d_out, int out_size, void* d_ws, size_t ws_size,
                              hipStream_t stream) {
    const float* pos  = (const float*)d_in[0];
    const float* spec = (const float*)d_in[1];
    const float* W1   = (const float*)d_in[2];
    const float* b1   = (const float*)d_in[3];
    const float* W2   = (const float*)d_in[4];
    const float* b2   = (const float*)d_in[5];
    const float* W3   = (const float*)d_in[6];
    const float* b3   = (const float*)d_in[7];

    unsigned int* counter = (unsigned int*)d_ws;          // 4 bytes, zeroed below
    float* e_at = (float*)((char*)d_ws + 256);            // 192 floats

    hipMemsetAsync(d_ws, 0, 4, stream);
    fused_kernel<<<NAT, 256, 0, stream>>>(pos, spec, W1, b1, W2, b2, W3, b3,
                                          e_at, counter, (float*)d_out);
}